// Round 11
// baseline (2939.988 us; speedup 1.0000x reference)
//
#include <hip/hip_runtime.h>
#include <hip/hip_bf16.h>

#define RNN_B 64
#define RNN_S 512
#define RNN_H 1024
#define BH (RNN_B * RNN_H)
#define L0_NBLK 64            // 16 col-slices x 4 batch-slices (64 cols x 16 rows each)
#define L1_NBLK 128           // 32 col-slices x 4 batch-slices (32 cols x 16 rows each)
#define NBLK (L0_NBLK + L1_NBLK)
#define FLAG_STRIDE 32
#define OUTS_ELEMS ((size_t)RNN_B * RNN_S * RNN_H)

typedef _Float16 f16;
typedef __attribute__((ext_vector_type(8))) _Float16 f16x8;
typedef __attribute__((ext_vector_type(8))) short bf16x8;
typedef __attribute__((ext_vector_type(4))) float f32x4;
typedef __attribute__((ext_vector_type(4))) int i32x4;

// raw buffer load, cachepolicy 17 = sc0|sc1: bypass L1/L2, read coherence point.
__device__ f32x4 __rnn_rawbufload_x4(i32x4 srsrc, int voffset, int soffset,
                                     int cachepolicy) __asm("llvm.amdgcn.raw.buffer.load.v4f32");

__device__ __forceinline__ i32x4 make_srd(const void* p, unsigned bytes) {
  i32x4 r;
  r[0] = (int)(unsigned)(unsigned long long)p;
  r[1] = (int)((unsigned long long)p >> 32);
  r[2] = (int)bytes;
  r[3] = 0x00020000;
  return r;
}

__device__ __forceinline__ f16x8 ld_h(i32x4 srd, int byteoff) {
  union { f32x4 f; f16x8 h; } u;
  u.f = __rnn_rawbufload_x4(srd, byteoff, 0, 17);
  return u.h;
}

// 2B write-through store to the coherence point (proven R5-R10)
__device__ __forceinline__ void st_sys_u16(void* p, unsigned v) {
  asm volatile("global_store_short %0, %1, off sc0 sc1" :: "v"(p), "v"(v) : "memory");
}

__device__ __forceinline__ unsigned f16bits(float f) {
  union { f16 h; unsigned short u; } v; v.h = (f16)f; return (unsigned)v.u;
}
__device__ __forceinline__ short f2bf(float f) {
  union { float f; unsigned u; } v; v.f = f;
  return (short)((v.u + 0x7FFFu + ((v.u >> 16) & 1u)) >> 16);
}
__device__ __forceinline__ float bf2f(short h) {
  union { unsigned u; float f; } v; v.u = ((unsigned)(unsigned short)h) << 16;
  return v.f;
}
__device__ __forceinline__ f32x4 mfma16b(bf16x8 a, bf16x8 b, f32x4 c) {
  return __builtin_amdgcn_mfma_f32_16x16x32_bf16(a, b, c, 0, 0, 0);
}
__device__ __forceinline__ f32x4 mfma16f(f16x8 a, f16x8 b, f32x4 c) {
  return __builtin_amdgcn_mfma_f32_16x16x32_f16(a, b, c, 0, 0, 0);
}
__device__ __forceinline__ void cvt8_hl(const float* f, bf16x8* hi, bf16x8* lo) {
  #pragma unroll
  for (int i = 0; i < 8; ++i) {
    short h = f2bf(f[i]);
    (*hi)[i] = h;
    (*lo)[i] = f2bf(f[i] - bf2f(h));
  }
}
__device__ __forceinline__ f16x8 cvt8f(const float* f) {
  f16x8 r;
  #pragma unroll
  for (int i = 0; i < 8; ++i) r[i] = (f16)f[i];
  return r;
}

// ---------- Kernel 1: A0 = x @ W_ih0^T + b_ih0 + b_hh0 (split-bf16 3-pass, ~fp32 accurate)
__global__ __launch_bounds__(256) void a0_gemm(
    const float* __restrict__ x, const float* __restrict__ Wih0,
    const float* __restrict__ bih0, const float* __restrict__ bhh0,
    float* __restrict__ A0, unsigned* __restrict__ flags)
{
  if (blockIdx.x == 0) {
    for (int i = threadIdx.x; i < 8 * FLAG_STRIDE; i += 256)   // 4 domains x 2 counters
      __hip_atomic_store(&flags[i], 0u, __ATOMIC_RELAXED, __HIP_MEMORY_SCOPE_SYSTEM);
  }
  const int bn = blockIdx.x & 7;
  const int bm = blockIdx.x >> 3;
  const int tid = threadIdx.x;
  const int lane = tid & 63;
  const int w = tid >> 6;
  const int wr = w >> 1, wc = w & 1;
  const int l15 = lane & 15, lq = lane >> 4;

  __shared__ short As[2][128][40];
  __shared__ short Bs[2][128][40];

  f32x4 acc[4][4] = {};

  const int sr = tid >> 1;
  const int sc = (tid & 1) << 4;
  const float* xp = x + (size_t)(bm * 128 + sr) * RNN_H + sc;
  const float* wp = Wih0 + (size_t)(bn * 128 + sr) * RNN_H + sc;

  for (int k0 = 0; k0 < RNN_H; k0 += 32) {
    float xa[16], wa[16];
    #pragma unroll
    for (int j = 0; j < 4; ++j) {
      *(float4*)&xa[j * 4] = *(const float4*)(xp + k0 + j * 4);
      *(float4*)&wa[j * 4] = *(const float4*)(wp + k0 + j * 4);
    }
    __syncthreads();
    bf16x8 h0, l0, h1, l1;
    cvt8_hl(&xa[0], &h0, &l0); cvt8_hl(&xa[8], &h1, &l1);
    *(bf16x8*)&As[0][sr][sc] = h0; *(bf16x8*)&As[1][sr][sc] = l0;
    *(bf16x8*)&As[0][sr][sc + 8] = h1; *(bf16x8*)&As[1][sr][sc + 8] = l1;
    cvt8_hl(&wa[0], &h0, &l0); cvt8_hl(&wa[8], &h1, &l1);
    *(bf16x8*)&Bs[0][sr][sc] = h0; *(bf16x8*)&Bs[1][sr][sc] = l0;
    *(bf16x8*)&Bs[0][sr][sc + 8] = h1; *(bf16x8*)&Bs[1][sr][sc + 8] = l1;
    __syncthreads();
    bf16x8 ah[4], al[4], bh[4], bl[4];
    #pragma unroll
    for (int i = 0; i < 4; ++i) {
      ah[i] = *(const bf16x8*)&As[0][wr * 64 + i * 16 + l15][lq * 8];
      al[i] = *(const bf16x8*)&As[1][wr * 64 + i * 16 + l15][lq * 8];
    }
    #pragma unroll
    for (int j = 0; j < 4; ++j) {
      bh[j] = *(const bf16x8*)&Bs[0][wc * 64 + j * 16 + l15][lq * 8];
      bl[j] = *(const bf16x8*)&Bs[1][wc * 64 + j * 16 + l15][lq * 8];
    }
    #pragma unroll
    for (int i = 0; i < 4; ++i)
      #pragma unroll
      for (int j = 0; j < 4; ++j) {
        acc[i][j] = mfma16b(ah[i], bh[j], acc[i][j]);
        acc[i][j] = mfma16b(al[i], bh[j], acc[i][j]);
        acc[i][j] = mfma16b(ah[i], bl[j], acc[i][j]);
      }
  }

  #pragma unroll
  for (int j = 0; j < 4; ++j) {
    const int col = bn * 128 + wc * 64 + j * 16 + l15;
    const float bias = bih0[col] + bhh0[col];
    #pragma unroll
    for (int i = 0; i < 4; ++i) {
      const int row0 = bm * 128 + wr * 64 + i * 16 + lq * 4;
      #pragma unroll
      for (int r = 0; r < 4; ++r)
        A0[(size_t)(row0 + r) * RNN_H + col] = acc[i][j][r] + bias;
    }
  }
}

// ---------- wait on 2 monotone domain counters: cntL0 >= tL0, cntL1 >= tL1.
// Lane 0 polls cntL0 line, lane 1 polls cntL1 line, others broadcast lane-0's line.
__device__ __forceinline__ void waitcnt2(const unsigned* fdom, int tL0, int tL1) {
  if (threadIdx.x < 64) {
    const int l = threadIdx.x;
    const unsigned* f = fdom + (l == 1 ? FLAG_STRIDE : 0);
    const int tgt = (l == 0) ? tL0 : (l == 1 ? tL1 : (-0x7FFFFFFF));
    while (!__all((int)__hip_atomic_load(f, __ATOMIC_RELAXED,
                                         __HIP_MEMORY_SCOPE_SYSTEM) >= tgt))
      __builtin_amdgcn_s_sleep(1);
  }
  __syncthreads();
}

// publish progress: drain this block's coherent h stores, block-arrive, +1 on domain counter
__device__ __forceinline__ void publish(unsigned* cnt) {
  asm volatile("s_waitcnt vmcnt(0)" ::: "memory");
  __syncthreads();
  if (threadIdx.x == 0)
    __hip_atomic_fetch_add(cnt, 1u, __ATOMIC_RELAXED, __HIP_MEMORY_SCOPE_SYSTEM);
}

// ---------- Kernel 2: persistent recurrence, batch-split x4 + K-split x4,
// per-domain monotone atomic counters, depth-D ping-pong (run-ahead D-1).
__global__ __launch_bounds__(256) void rnn_rec(
    const float* __restrict__ Whh0,
    const float* __restrict__ Wih1, const float* __restrict__ bih1,
    const float* __restrict__ Whh1, const float* __restrict__ bhh1,
    float* outs,             // d_out: A0 (read), layer-1 outs (write), hT tail
    f16* __restrict__ h0buf, // ws: [D][B][H] fp16 ring
    f16* __restrict__ h1buf, // ws: [D][B][H] fp16 ring
    unsigned* flags, int dmask)
{
  const int bid = blockIdx.x;
  const bool isL0 = bid < L0_NBLK;
  const int tid = threadIdx.x;
  const int w = tid >> 6;         // K-slice 0..3 (256 elems each)
  const int lane = tid & 63;
  const int l15 = lane & 15;
  const int lq = lane >> 4;
  const int swz = l15 & 7;
  const int dlag = dmask;         // D-1 run-ahead slack

  int b0, n0, bs, cs;
  if (isL0) { bs = bid >> 4; cs = bid & 15; b0 = bs * 16; n0 = cs * 64; }
  else { const int b2 = bid - L0_NBLK; bs = b2 >> 5; cs = b2 & 31; b0 = bs * 16; n0 = cs * 32; }

  unsigned* fdom = flags + bs * 2 * FLAG_STRIDE;            // [cntL0 | cntL1]
  unsigned* mycnt = fdom + (isL0 ? 0 : FLAG_STRIDE);

  const unsigned HBYT = (unsigned)(dmask + 1) * BH * 2u;
  const i32x4 srd_h0 = make_srd(h0buf, HBYT);
  const i32x4 srd_h1 = make_srd(h1buf, HBYT);

  __shared__ __align__(16) f16 Ws[2 * 32 * RNN_H];   // 128 KiB weights (fp16, swizzled)
  __shared__ float red[4][16][64];                    // 16 KiB K-split reduction

  // ---- stage weights fp32 -> fp16 into LDS, 16B-chunk swizzle: chunk c of row n -> c^(n&7)
  if (isL0) {
    const int n = tid >> 2;             // 0..63
    const int kb = (tid & 3) * 256;
    const float* src = Whh0 + (size_t)(n0 + n) * RNN_H + kb;
    f16* dst = Ws + n * RNN_H;
    #pragma unroll 4
    for (int j = 0; j < 32; ++j) {
      float tmp[8];
      *(float4*)&tmp[0] = *(const float4*)(src + j * 8);
      *(float4*)&tmp[4] = *(const float4*)(src + j * 8 + 4);
      const int c = (kb >> 3) + j;
      *(f16x8*)&dst[((c ^ (n & 7)) << 3)] = cvt8f(tmp);
    }
  } else {
    const int n = tid >> 3;             // 0..31
    const int kb = (tid & 7) * 128;
    #pragma unroll
    for (int m = 0; m < 2; ++m) {
      const float* src = (m ? Whh1 : Wih1) + (size_t)(n0 + n) * RNN_H + kb;
      f16* dst = Ws + m * 32 * RNN_H + n * RNN_H;
      #pragma unroll 4
      for (int j = 0; j < 16; ++j) {
        float tmp[8];
        *(float4*)&tmp[0] = *(const float4*)(src + j * 8);
        *(float4*)&tmp[4] = *(const float4*)(src + j * 8 + 4);
        const int c = (kb >> 3) + j;
        *(f16x8*)&dst[((c ^ (n & 7)) << 3)] = cvt8f(tmp);
      }
    }
  }

  float* hT = outs + OUTS_ELEMS;

  // combine-phase role
  int ccol, crg;
  float bias1s = 0.f;
  if (isL0) { ccol = tid & 63; crg = tid >> 6; }        // rows crg*4 + r
  else      { ccol = tid & 31; crg = tid >> 5;          // rows crg*2 + r
              bias1s = bih1[n0 + ccol] + bhh1[n0 + ccol]; }
  __syncthreads();

  if (isL0) {
    float a0v[4];
    #pragma unroll
    for (int r = 0; r < 4; ++r)
      a0v[r] = outs[((size_t)(b0 + crg * 4 + r) * RNN_S + 0) * RNN_H + n0 + ccol];

    for (int p = 0; p < RNN_S; ++p) {
      // need: all L0 done step p-1 (cntL0 >= 16p); WAR: all L1 done step p-D (cntL1 >= 32(p-dlag))
      waitcnt2(fdom, 16 * p, 32 * (p - dlag));
      if (p > 0) {
        const int hb = (((p - 1) & dmask) * BH + (b0 + l15) * RNN_H + w * 256 + lq * 8) * 2;
        f32x4 acc[4] = {};
        #pragma unroll
        for (int ks = 0; ks < 8; ++ks) {
          f16x8 hx = ld_h(srd_h0, hb + ks * 64);
          const int c = ((w * 32 + ks * 4 + lq) ^ swz) << 3;
          #pragma unroll
          for (int ct = 0; ct < 4; ++ct)
            acc[ct] = mfma16f(hx, *(const f16x8*)&Ws[(ct * 16 + l15) * RNN_H + c], acc[ct]);
        }
        #pragma unroll
        for (int ct = 0; ct < 4; ++ct)
          #pragma unroll
          for (int r = 0; r < 4; ++r)
            red[w][lq * 4 + r][ct * 16 + l15] = acc[ct][r];
      }
      __syncthreads();
      float vals[4];
      #pragma unroll
      for (int r = 0; r < 4; ++r) {
        const int row = crg * 4 + r;
        float s = a0v[r];
        if (p > 0)
          s += red[0][row][ccol] + red[1][row][ccol] + red[2][row][ccol] + red[3][row][ccol];
        vals[r] = tanhf(s);
        st_sys_u16(&h0buf[(size_t)(p & dmask) * BH + (size_t)(b0 + row) * RNN_H + n0 + ccol],
                   f16bits(vals[r]));
      }
      publish(mycnt);                      // release h0(p) ASAP
      if (p == RNN_S - 1) {                // off critical path
        #pragma unroll
        for (int r = 0; r < 4; ++r)
          hT[(size_t)(b0 + crg * 4 + r) * RNN_H + n0 + ccol] = vals[r];
      }
      if (p + 1 < RNN_S) {                 // A0 prefetch overlaps next wait
        #pragma unroll
        for (int r = 0; r < 4; ++r)
          a0v[r] = outs[((size_t)(b0 + crg * 4 + r) * RNN_S + (p + 1)) * RNN_H + n0 + ccol];
      }
    }
  } else {
    for (int t = 0; t < RNN_S; ++t) {
      // need: h0(t) written (cntL0 >= 16(t+1)); h1(t-1) written (cntL1 >= 32t)
      waitcnt2(fdom, 16 * (t + 1), 32 * t);
      const int hb0 = ((t & dmask) * BH + (b0 + l15) * RNN_H + w * 256 + lq * 8) * 2;
      f32x4 acc[2] = {};
      if (t > 0) {
        const int hb1 = (((t - 1) & dmask) * BH + (b0 + l15) * RNN_H + w * 256 + lq * 8) * 2;
        #pragma unroll
        for (int ks = 0; ks < 8; ++ks) {
          f16x8 hx = ld_h(srd_h0, hb0 + ks * 64);
          f16x8 gx = ld_h(srd_h1, hb1 + ks * 64);
          const int c = ((w * 32 + ks * 4 + lq) ^ swz) << 3;
          #pragma unroll
          for (int ct = 0; ct < 2; ++ct) {
            acc[ct] = mfma16f(hx, *(const f16x8*)&Ws[(ct * 16 + l15) * RNN_H + c], acc[ct]);
            acc[ct] = mfma16f(gx, *(const f16x8*)&Ws[32 * RNN_H + (ct * 16 + l15) * RNN_H + c], acc[ct]);
          }
        }
      } else {
        #pragma unroll
        for (int ks = 0; ks < 8; ++ks) {
          f16x8 hx = ld_h(srd_h0, hb0 + ks * 64);
          const int c = ((w * 32 + ks * 4 + lq) ^ swz) << 3;
          #pragma unroll
          for (int ct = 0; ct < 2; ++ct)
            acc[ct] = mfma16f(hx, *(const f16x8*)&Ws[(ct * 16 + l15) * RNN_H + c], acc[ct]);
        }
      }
      #pragma unroll
      for (int ct = 0; ct < 2; ++ct)
        #pragma unroll
        for (int r = 0; r < 4; ++r)
          red[w][lq * 4 + r][ct * 16 + l15] = acc[ct][r];
      __syncthreads();
      float v2[2];
      #pragma unroll
      for (int r = 0; r < 2; ++r) {
        const int row = crg * 2 + r;
        float s = bias1s + red[0][row][ccol] + red[1][row][ccol]
                         + red[2][row][ccol] + red[3][row][ccol];
        v2[r] = tanhf(s);
        st_sys_u16(&h1buf[(size_t)(t & dmask) * BH + (size_t)(b0 + row) * RNN_H + n0 + ccol],
                   f16bits(v2[r]));
      }
      publish(mycnt);                      // release h1(t) ASAP
      #pragma unroll
      for (int r = 0; r < 2; ++r) {        // outs/hT off critical path
        const int row = crg * 2 + r;
        outs[((size_t)(b0 + row) * RNN_S + t) * RNN_H + n0 + ccol] = v2[r];
        if (t == RNN_S - 1)
          hT[(size_t)BH + (size_t)(b0 + row) * RNN_H + n0 + ccol] = v2[r];
      }
    }
  }
}

extern "C" void kernel_launch(void* const* d_in, const int* in_sizes, int n_in,
                              void* d_out, int out_size, void* d_ws, size_t ws_size,
                              hipStream_t stream) {
  const float* x    = (const float*)d_in[0];
  const float* Wih0 = (const float*)d_in[1];
  const float* bih0 = (const float*)d_in[2];
  const float* Whh0 = (const float*)d_in[3];
  const float* bhh0 = (const float*)d_in[4];
  const float* Wih1 = (const float*)d_in[5];
  const float* bih1 = (const float*)d_in[6];
  const float* Whh1 = (const float*)d_in[7];
  const float* bhh1 = (const float*)d_in[8];
  float* outs = (float*)d_out;

  // ws layout: [counters 32KiB][h0buf D*128KiB][h1buf D*128KiB]
  const size_t flagBytes = 32768;
  const size_t need4 = flagBytes + 2 * (size_t)4 * BH * sizeof(f16);   // ~1.03 MiB
  const int D = (ws_size >= need4) ? 4 : 2;
  unsigned* flags = (unsigned*)d_ws;
  f16* h0buf = (f16*)((char*)d_ws + flagBytes);
  f16* h1buf = h0buf + (size_t)D * BH;

  a0_gemm<<<2048, 256, 0, stream>>>(x, Wih0, bih0, bhh0, outs, flags);
  rnn_rec<<<NBLK, 256, 0, stream>>>(Whh0, Wih1, bih1, Whh1, bhh1, outs,
                                    h0buf, h1buf, flags, D - 1);
}

// Round 12
// 2408.756 us; speedup vs baseline: 1.2205x; 1.2205x over previous
//
#include <hip/hip_runtime.h>
#include <hip/hip_bf16.h>

#define RNN_B 64
#define RNN_S 512
#define RNN_H 1024
#define BH (RNN_B * RNN_H)
#define L0_NBLK 64            // 16 col-slices x 4 batch-slices (64 cols x 16 rows each)
#define L1_NBLK 128           // 32 col-slices x 4 batch-slices (32 cols x 16 rows each)
#define NBLK (L0_NBLK + L1_NBLK)
#define NFLAGS 192            // 4 domains x 48 flags
#define FLAG_STRIDE 32
#define OUTS_ELEMS ((size_t)RNN_B * RNN_S * RNN_H)

typedef _Float16 f16;
typedef __attribute__((ext_vector_type(8))) _Float16 f16x8;
typedef __attribute__((ext_vector_type(8))) short bf16x8;
typedef __attribute__((ext_vector_type(4))) float f32x4;
typedef __attribute__((ext_vector_type(2))) float f32x2;
typedef __attribute__((ext_vector_type(4))) int i32x4;

// raw buffer load, cachepolicy 17 = sc0|sc1: bypass L1/L2, read coherence point.
__device__ f32x4 __rnn_rawbufload_x4(i32x4 srsrc, int voffset, int soffset,
                                     int cachepolicy) __asm("llvm.amdgcn.raw.buffer.load.v4f32");

__device__ __forceinline__ i32x4 make_srd(const void* p, unsigned bytes) {
  i32x4 r;
  r[0] = (int)(unsigned)(unsigned long long)p;
  r[1] = (int)((unsigned long long)p >> 32);
  r[2] = (int)bytes;
  r[3] = 0x00020000;
  return r;
}

__device__ __forceinline__ f16x8 ld_h(i32x4 srd, int byteoff) {
  union { f32x4 f; f16x8 h; } u;
  u.f = __rnn_rawbufload_x4(srd, byteoff, 0, 17);
  return u.h;
}

// write-through stores to the coherence point (proven R5-R11)
__device__ __forceinline__ void st_sys_u32(void* p, unsigned v) {
  asm volatile("global_store_dword %0, %1, off sc0 sc1" :: "v"(p), "v"(v) : "memory");
}
__device__ __forceinline__ void st_sys_u64(void* p, unsigned long long v) {
  asm volatile("global_store_dwordx2 %0, %1, off sc0 sc1" :: "v"(p), "v"(v) : "memory");
}

__device__ __forceinline__ unsigned pack2f16(float a, float b) {
  union { f16 h[2]; unsigned u; } v;
  v.h[0] = (f16)a; v.h[1] = (f16)b;
  return v.u;
}
__device__ __forceinline__ unsigned long long pack4f16(const float* f) {
  union { f16 h[4]; unsigned long long u; } v;
  #pragma unroll
  for (int i = 0; i < 4; ++i) v.h[i] = (f16)f[i];
  return v.u;
}

__device__ __forceinline__ short f2bf(float f) {
  union { float f; unsigned u; } v; v.f = f;
  return (short)((v.u + 0x7FFFu + ((v.u >> 16) & 1u)) >> 16);
}
__device__ __forceinline__ float bf2f(short h) {
  union { unsigned u; float f; } v; v.u = ((unsigned)(unsigned short)h) << 16;
  return v.f;
}
__device__ __forceinline__ f32x4 mfma16b(bf16x8 a, bf16x8 b, f32x4 c) {
  return __builtin_amdgcn_mfma_f32_16x16x32_bf16(a, b, c, 0, 0, 0);
}
__device__ __forceinline__ f32x4 mfma16f(f16x8 a, f16x8 b, f32x4 c) {
  return __builtin_amdgcn_mfma_f32_16x16x32_f16(a, b, c, 0, 0, 0);
}
__device__ __forceinline__ void cvt8_hl(const float* f, bf16x8* hi, bf16x8* lo) {
  #pragma unroll
  for (int i = 0; i < 8; ++i) {
    short h = f2bf(f[i]);
    (*hi)[i] = h;
    (*lo)[i] = f2bf(f[i] - bf2f(h));
  }
}
__device__ __forceinline__ f16x8 cvt8f(const float* f) {
  f16x8 r;
  #pragma unroll
  for (int i = 0; i < 8; ++i) r[i] = (f16)f[i];
  return r;
}

// ---------- Kernel 1: A0 = x @ W_ih0^T + b_ih0 + b_hh0 (split-bf16 3-pass, ~fp32 accurate)
__global__ __launch_bounds__(256) void a0_gemm(
    const float* __restrict__ x, const float* __restrict__ Wih0,
    const float* __restrict__ bih0, const float* __restrict__ bhh0,
    float* __restrict__ A0, unsigned* __restrict__ flags)
{
  if (blockIdx.x == 0) {
    for (int i = threadIdx.x; i < NFLAGS * FLAG_STRIDE; i += 256)
      __hip_atomic_store(&flags[i], 0u, __ATOMIC_RELAXED, __HIP_MEMORY_SCOPE_SYSTEM);
  }
  const int bn = blockIdx.x & 7;
  const int bm = blockIdx.x >> 3;
  const int tid = threadIdx.x;
  const int lane = tid & 63;
  const int w = tid >> 6;
  const int wr = w >> 1, wc = w & 1;
  const int l15 = lane & 15, lq = lane >> 4;

  __shared__ short As[2][128][40];
  __shared__ short Bs[2][128][40];

  f32x4 acc[4][4] = {};

  const int sr = tid >> 1;
  const int sc = (tid & 1) << 4;
  const float* xp = x + (size_t)(bm * 128 + sr) * RNN_H + sc;
  const float* wp = Wih0 + (size_t)(bn * 128 + sr) * RNN_H + sc;

  for (int k0 = 0; k0 < RNN_H; k0 += 32) {
    float xa[16], wa[16];
    #pragma unroll
    for (int j = 0; j < 4; ++j) {
      *(float4*)&xa[j * 4] = *(const float4*)(xp + k0 + j * 4);
      *(float4*)&wa[j * 4] = *(const float4*)(wp + k0 + j * 4);
    }
    __syncthreads();
    bf16x8 h0, l0, h1, l1;
    cvt8_hl(&xa[0], &h0, &l0); cvt8_hl(&xa[8], &h1, &l1);
    *(bf16x8*)&As[0][sr][sc] = h0; *(bf16x8*)&As[1][sr][sc] = l0;
    *(bf16x8*)&As[0][sr][sc + 8] = h1; *(bf16x8*)&As[1][sr][sc + 8] = l1;
    cvt8_hl(&wa[0], &h0, &l0); cvt8_hl(&wa[8], &h1, &l1);
    *(bf16x8*)&Bs[0][sr][sc] = h0; *(bf16x8*)&Bs[1][sr][sc] = l0;
    *(bf16x8*)&Bs[0][sr][sc + 8] = h1; *(bf16x8*)&Bs[1][sr][sc + 8] = l1;
    __syncthreads();
    bf16x8 ah[4], al[4], bh[4], bl[4];
    #pragma unroll
    for (int i = 0; i < 4; ++i) {
      ah[i] = *(const bf16x8*)&As[0][wr * 64 + i * 16 + l15][lq * 8];
      al[i] = *(const bf16x8*)&As[1][wr * 64 + i * 16 + l15][lq * 8];
    }
    #pragma unroll
    for (int j = 0; j < 4; ++j) {
      bh[j] = *(const bf16x8*)&Bs[0][wc * 64 + j * 16 + l15][lq * 8];
      bl[j] = *(const bf16x8*)&Bs[1][wc * 64 + j * 16 + l15][lq * 8];
    }
    #pragma unroll
    for (int i = 0; i < 4; ++i)
      #pragma unroll
      for (int j = 0; j < 4; ++j) {
        acc[i][j] = mfma16b(ah[i], bh[j], acc[i][j]);
        acc[i][j] = mfma16b(al[i], bh[j], acc[i][j]);
        acc[i][j] = mfma16b(ah[i], bl[j], acc[i][j]);
      }
  }

  #pragma unroll
  for (int j = 0; j < 4; ++j) {
    const int col = bn * 128 + wc * 64 + j * 16 + l15;
    const float bias = bih0[col] + bhh0[col];
    #pragma unroll
    for (int i = 0; i < 4; ++i) {
      const int row0 = bm * 128 + wr * 64 + i * 16 + lq * 4;
      #pragma unroll
      for (int r = 0; r < 4; ++r)
        A0[(size_t)(row0 + r) * RNN_H + col] = acc[i][j][r] + bias;
    }
  }
}

// ---------- per-domain wait (R10-proven): lanes 0-15 poll L0 flags, 16-47 poll L1 flags
__device__ __forceinline__ void waitflags(const unsigned* fbase, int tL0, int tL1) {
  if (threadIdx.x < 64) {
    const int l = threadIdx.x;
    const unsigned* f = fbase + (l < 48 ? l : 0) * FLAG_STRIDE;
    const int tgt = (l < 16) ? tL0 : (l < 48 ? tL1 : (-0x7FFFFFFF));
    while (!__all((int)__hip_atomic_load(f, __ATOMIC_RELAXED,
                                         __HIP_MEMORY_SCOPE_SYSTEM) >= tgt))
      __builtin_amdgcn_s_sleep(1);
  }
  __syncthreads();
}

// publish progress (R10-proven): drain h stores, block-arrive, store per-block flag
__device__ __forceinline__ void publish(unsigned* slot, unsigned v) {
  asm volatile("s_waitcnt vmcnt(0)" ::: "memory");
  __syncthreads();
  if (threadIdx.x == 0)
    __hip_atomic_store(slot, v, __ATOMIC_RELAXED, __HIP_MEMORY_SCOPE_SYSTEM);
}

// ---------- Kernel 2: persistent recurrence, batch-split x4 + K-split x4,
// per-batch-slice flags, depth-D ping-pong; publish-early + vectorized combine.
__global__ __launch_bounds__(256) void rnn_rec(
    const float* __restrict__ Whh0,
    const float* __restrict__ Wih1, const float* __restrict__ bih1,
    const float* __restrict__ Whh1, const float* __restrict__ bhh1,
    float* outs,             // d_out: A0 (read), layer-1 outs (write), hT tail
    f16* __restrict__ h0buf, // ws: [D][B][H] fp16 ring
    f16* __restrict__ h1buf, // ws: [D][B][H] fp16 ring
    unsigned* flags, int dmask)
{
  const int bid = blockIdx.x;
  const bool isL0 = bid < L0_NBLK;
  const int tid = threadIdx.x;
  const int w = tid >> 6;         // K-slice 0..3 (256 elems each)
  const int lane = tid & 63;
  const int l15 = lane & 15;
  const int lq = lane >> 4;
  const int swz = l15 & 7;
  const int dlag = dmask;         // D-1 run-ahead slack

  int b0, n0, bs, cs;
  if (isL0) { bs = bid >> 4; cs = bid & 15; b0 = bs * 16; n0 = cs * 64; }
  else { const int b2 = bid - L0_NBLK; bs = b2 >> 5; cs = b2 & 31; b0 = bs * 16; n0 = cs * 32; }

  unsigned* fbase = flags + bs * 48 * FLAG_STRIDE;
  unsigned* myflag = fbase + (isL0 ? cs : 16 + cs) * FLAG_STRIDE;

  const unsigned HBYT = (unsigned)(dmask + 1) * BH * 2u;
  const i32x4 srd_h0 = make_srd(h0buf, HBYT);
  const i32x4 srd_h1 = make_srd(h1buf, HBYT);

  __shared__ __align__(16) f16 Ws[2 * 32 * RNN_H];   // 128 KiB weights (fp16, swizzled)
  __shared__ __align__(16) float red[4][16][64];      // 16 KiB K-split reduction

  // ---- stage weights fp32 -> fp16 into LDS, 16B-chunk swizzle: chunk c of row n -> c^(n&7)
  if (isL0) {
    const int n = tid >> 2;             // 0..63
    const int kb = (tid & 3) * 256;
    const float* src = Whh0 + (size_t)(n0 + n) * RNN_H + kb;
    f16* dst = Ws + n * RNN_H;
    #pragma unroll 4
    for (int j = 0; j < 32; ++j) {
      float tmp[8];
      *(float4*)&tmp[0] = *(const float4*)(src + j * 8);
      *(float4*)&tmp[4] = *(const float4*)(src + j * 8 + 4);
      const int c = (kb >> 3) + j;
      *(f16x8*)&dst[((c ^ (n & 7)) << 3)] = cvt8f(tmp);
    }
  } else {
    const int n = tid >> 3;             // 0..31
    const int kb = (tid & 7) * 128;
    #pragma unroll
    for (int m = 0; m < 2; ++m) {
      const float* src = (m ? Whh1 : Wih1) + (size_t)(n0 + n) * RNN_H + kb;
      f16* dst = Ws + m * 32 * RNN_H + n * RNN_H;
      #pragma unroll 4
      for (int j = 0; j < 16; ++j) {
        float tmp[8];
        *(float4*)&tmp[0] = *(const float4*)(src + j * 8);
        *(float4*)&tmp[4] = *(const float4*)(src + j * 8 + 4);
        const int c = (kb >> 3) + j;
        *(f16x8*)&dst[((c ^ (n & 7)) << 3)] = cvt8f(tmp);
      }
    }
  }

  float* hT = outs + OUTS_ELEMS;

  // combine-phase role: one row, a small contiguous col-group per thread
  const int crow = tid & 15;
  const int cg = tid >> 4;            // L0: 4 cols per group; L1: 2 cols per group
  float bias1a = 0.f, bias1b = 0.f;
  if (!isL0) {
    bias1a = bih1[n0 + cg * 2]     + bhh1[n0 + cg * 2];
    bias1b = bih1[n0 + cg * 2 + 1] + bhh1[n0 + cg * 2 + 1];
  }
  __syncthreads();

  if (isL0) {
    f32x4 a0v = *(const f32x4*)&outs[((size_t)(b0 + crow) * RNN_S + 0) * RNN_H + n0 + cg * 4];

    for (int p = 0; p < RNN_S; ++p) {
      // need: all L0 done step p-1; WAR: all L1 done step p-D
      waitflags(fbase, p, p - dlag);
      if (p > 0) {
        const int hb = (((p - 1) & dmask) * BH + (b0 + l15) * RNN_H + w * 256 + lq * 8) * 2;
        f32x4 acc[4] = {};
        #pragma unroll
        for (int ks = 0; ks < 8; ++ks) {
          f16x8 hx = ld_h(srd_h0, hb + ks * 64);
          const int c = ((w * 32 + ks * 4 + lq) ^ swz) << 3;
          #pragma unroll
          for (int ct = 0; ct < 4; ++ct)
            acc[ct] = mfma16f(hx, *(const f16x8*)&Ws[(ct * 16 + l15) * RNN_H + c], acc[ct]);
        }
        #pragma unroll
        for (int ct = 0; ct < 4; ++ct)
          #pragma unroll
          for (int r = 0; r < 4; ++r)
            red[w][lq * 4 + r][ct * 16 + l15] = acc[ct][r];
      }
      __syncthreads();
      float vals[4];
      #pragma unroll
      for (int j = 0; j < 4; ++j) {
        float s = a0v[j];
        if (p > 0)
          s += red[0][crow][cg * 4 + j] + red[1][crow][cg * 4 + j]
             + red[2][crow][cg * 4 + j] + red[3][crow][cg * 4 + j];
        vals[j] = tanhf(s);
      }
      st_sys_u64(&h0buf[(size_t)(p & dmask) * BH + (size_t)(b0 + crow) * RNN_H + n0 + cg * 4],
                 pack4f16(vals));
      publish(myflag, (unsigned)(p + 1));    // release h0(p) ASAP
      if (p == RNN_S - 1) {                  // off critical path
        f32x4 hv = { vals[0], vals[1], vals[2], vals[3] };
        *(f32x4*)&hT[(size_t)(b0 + crow) * RNN_H + n0 + cg * 4] = hv;
      }
      if (p + 1 < RNN_S)                     // A0 prefetch overlaps next wait
        a0v = *(const f32x4*)&outs[((size_t)(b0 + crow) * RNN_S + (p + 1)) * RNN_H + n0 + cg * 4];
    }
  } else {
    for (int t = 0; t < RNN_S; ++t) {
      // need: h0(t) written; h1(t-1) written
      waitflags(fbase, t + 1, t);
      const int hb0 = ((t & dmask) * BH + (b0 + l15) * RNN_H + w * 256 + lq * 8) * 2;
      f32x4 acc[2] = {};
      if (t > 0) {
        const int hb1 = (((t - 1) & dmask) * BH + (b0 + l15) * RNN_H + w * 256 + lq * 8) * 2;
        #pragma unroll
        for (int ks = 0; ks < 8; ++ks) {
          f16x8 hx = ld_h(srd_h0, hb0 + ks * 64);
          f16x8 gx = ld_h(srd_h1, hb1 + ks * 64);
          const int c = ((w * 32 + ks * 4 + lq) ^ swz) << 3;
          #pragma unroll
          for (int ct = 0; ct < 2; ++ct) {
            acc[ct] = mfma16f(hx, *(const f16x8*)&Ws[(ct * 16 + l15) * RNN_H + c], acc[ct]);
            acc[ct] = mfma16f(gx, *(const f16x8*)&Ws[32 * RNN_H + (ct * 16 + l15) * RNN_H + c], acc[ct]);
          }
        }
      } else {
        #pragma unroll
        for (int ks = 0; ks < 8; ++ks) {
          f16x8 hx = ld_h(srd_h0, hb0 + ks * 64);
          const int c = ((w * 32 + ks * 4 + lq) ^ swz) << 3;
          #pragma unroll
          for (int ct = 0; ct < 2; ++ct)
            acc[ct] = mfma16f(hx, *(const f16x8*)&Ws[(ct * 16 + l15) * RNN_H + c], acc[ct]);
        }
      }
      #pragma unroll
      for (int ct = 0; ct < 2; ++ct)
        #pragma unroll
        for (int r = 0; r < 4; ++r)
          red[w][lq * 4 + r][ct * 16 + l15] = acc[ct][r];
      __syncthreads();
      float s0 = bias1a + red[0][crow][cg * 2]     + red[1][crow][cg * 2]
                        + red[2][crow][cg * 2]     + red[3][crow][cg * 2];
      float s1 = bias1b + red[0][crow][cg * 2 + 1] + red[1][crow][cg * 2 + 1]
                        + red[2][crow][cg * 2 + 1] + red[3][crow][cg * 2 + 1];
      const float v0 = tanhf(s0), v1 = tanhf(s1);
      st_sys_u32(&h1buf[(size_t)(t & dmask) * BH + (size_t)(b0 + crow) * RNN_H + n0 + cg * 2],
                 pack2f16(v0, v1));
      publish(myflag, (unsigned)(t + 1));    // release h1(t) ASAP
      {                                      // outs/hT off critical path
        f32x2 ov = { v0, v1 };
        *(f32x2*)&outs[((size_t)(b0 + crow) * RNN_S + t) * RNN_H + n0 + cg * 2] = ov;
        if (t == RNN_S - 1)
          *(f32x2*)&hT[(size_t)BH + (size_t)(b0 + crow) * RNN_H + n0 + cg * 2] = ov;
      }
    }
  }
}

extern "C" void kernel_launch(void* const* d_in, const int* in_sizes, int n_in,
                              void* d_out, int out_size, void* d_ws, size_t ws_size,
                              hipStream_t stream) {
  const float* x    = (const float*)d_in[0];
  const float* Wih0 = (const float*)d_in[1];
  const float* bih0 = (const float*)d_in[2];
  const float* Whh0 = (const float*)d_in[3];
  const float* bhh0 = (const float*)d_in[4];
  const float* Wih1 = (const float*)d_in[5];
  const float* bih1 = (const float*)d_in[6];
  const float* Whh1 = (const float*)d_in[7];
  const float* bhh1 = (const float*)d_in[8];
  float* outs = (float*)d_out;

  // ws layout: [flags 32KiB][h0buf D*128KiB][h1buf D*128KiB]
  const size_t flagBytes = 32768;
  const size_t need4 = flagBytes + 2 * (size_t)4 * BH * sizeof(f16);   // ~1.03 MiB
  const int D = (ws_size >= need4) ? 4 : 2;
  unsigned* flags = (unsigned*)d_ws;
  f16* h0buf = (f16*)((char*)d_ws + flagBytes);
  f16* h1buf = h0buf + (size_t)D * BH;

  a0_gemm<<<2048, 256, 0, stream>>>(x, Wih0, bih0, bhh0, outs, flags);
  rnn_rec<<<NBLK, 256, 0, stream>>>(Whh0, Wih1, bih1, Whh1, bhh1, outs,
                                    h0buf, h1buf, flags, D - 1);
}

// Round 13
// 2201.429 us; speedup vs baseline: 1.3355x; 1.0942x over previous
//
#include <hip/hip_runtime.h>
#include <hip/hip_bf16.h>

#define RNN_B 64
#define RNN_S 512
#define RNN_H 1024
#define BH (RNN_B * RNN_H)
#define L0_NBLK 64            // 16 col-slices x 4 batch-slices (64 cols x 16 rows each)
#define L1_NBLK 128           // 32 col-slices x 4 batch-slices (32 cols x 16 rows each)
#define NBLK (L0_NBLK + L1_NBLK)
#define NFLAGS 192            // 4 domains x 48 flags
#define FLAG_STRIDE 32
#define OUTS_ELEMS ((size_t)RNN_B * RNN_S * RNN_H)

typedef _Float16 f16;
typedef __attribute__((ext_vector_type(8))) _Float16 f16x8;
typedef __attribute__((ext_vector_type(8))) short bf16x8;
typedef __attribute__((ext_vector_type(4))) float f32x4;
typedef __attribute__((ext_vector_type(2))) float f32x2;
typedef __attribute__((ext_vector_type(4))) int i32x4;

// raw buffer load, cachepolicy 17 = sc0|sc1: bypass L1/L2, read coherence point.
__device__ f32x4 __rnn_rawbufload_x4(i32x4 srsrc, int voffset, int soffset,
                                     int cachepolicy) __asm("llvm.amdgcn.raw.buffer.load.v4f32");

__device__ __forceinline__ i32x4 make_srd(const void* p, unsigned bytes) {
  i32x4 r;
  r[0] = (int)(unsigned)(unsigned long long)p;
  r[1] = (int)((unsigned long long)p >> 32);
  r[2] = (int)bytes;
  r[3] = 0x00020000;
  return r;
}

__device__ __forceinline__ f16x8 ld_h(i32x4 srd, int byteoff) {
  union { f32x4 f; f16x8 h; } u;
  u.f = __rnn_rawbufload_x4(srd, byteoff, 0, 17);
  return u.h;
}

// write-through stores to the coherence point (proven R5-R12)
__device__ __forceinline__ void st_sys_u32(void* p, unsigned v) {
  asm volatile("global_store_dword %0, %1, off sc0 sc1" :: "v"(p), "v"(v) : "memory");
}
__device__ __forceinline__ void st_sys_u64(void* p, unsigned long long v) {
  asm volatile("global_store_dwordx2 %0, %1, off sc0 sc1" :: "v"(p), "v"(v) : "memory");
}

__device__ __forceinline__ unsigned pack2f16(float a, float b) {
  union { f16 h[2]; unsigned u; } v;
  v.h[0] = (f16)a; v.h[1] = (f16)b;
  return v.u;
}
__device__ __forceinline__ unsigned long long pack4f16(const float* f) {
  union { f16 h[4]; unsigned long long u; } v;
  #pragma unroll
  for (int i = 0; i < 4; ++i) v.h[i] = (f16)f[i];
  return v.u;
}

__device__ __forceinline__ short f2bf(float f) {
  union { float f; unsigned u; } v; v.f = f;
  return (short)((v.u + 0x7FFFu + ((v.u >> 16) & 1u)) >> 16);
}
__device__ __forceinline__ float bf2f(short h) {
  union { unsigned u; float f; } v; v.u = ((unsigned)(unsigned short)h) << 16;
  return v.f;
}
__device__ __forceinline__ f32x4 mfma16b(bf16x8 a, bf16x8 b, f32x4 c) {
  return __builtin_amdgcn_mfma_f32_16x16x32_bf16(a, b, c, 0, 0, 0);
}
__device__ __forceinline__ f32x4 mfma16f(f16x8 a, f16x8 b, f32x4 c) {
  return __builtin_amdgcn_mfma_f32_16x16x32_f16(a, b, c, 0, 0, 0);
}
__device__ __forceinline__ void cvt8_hl(const float* f, bf16x8* hi, bf16x8* lo) {
  #pragma unroll
  for (int i = 0; i < 8; ++i) {
    short h = f2bf(f[i]);
    (*hi)[i] = h;
    (*lo)[i] = f2bf(f[i] - bf2f(h));
  }
}
__device__ __forceinline__ f16x8 cvt8f(const float* f) {
  f16x8 r;
  #pragma unroll
  for (int i = 0; i < 8; ++i) r[i] = (f16)f[i];
  return r;
}

// ---------- Kernel 1: A0 = x @ W_ih0^T + b_ih0 + b_hh0 (split-bf16 3-pass, ~fp32 accurate)
__global__ __launch_bounds__(256) void a0_gemm(
    const float* __restrict__ x, const float* __restrict__ Wih0,
    const float* __restrict__ bih0, const float* __restrict__ bhh0,
    float* __restrict__ A0, unsigned* __restrict__ flags)
{
  if (blockIdx.x == 0) {
    for (int i = threadIdx.x; i < NFLAGS * FLAG_STRIDE; i += 256)
      __hip_atomic_store(&flags[i], 0u, __ATOMIC_RELAXED, __HIP_MEMORY_SCOPE_SYSTEM);
  }
  const int bn = blockIdx.x & 7;
  const int bm = blockIdx.x >> 3;
  const int tid = threadIdx.x;
  const int lane = tid & 63;
  const int w = tid >> 6;
  const int wr = w >> 1, wc = w & 1;
  const int l15 = lane & 15, lq = lane >> 4;

  __shared__ short As[2][128][40];
  __shared__ short Bs[2][128][40];

  f32x4 acc[4][4] = {};

  const int sr = tid >> 1;
  const int sc = (tid & 1) << 4;
  const float* xp = x + (size_t)(bm * 128 + sr) * RNN_H + sc;
  const float* wp = Wih0 + (size_t)(bn * 128 + sr) * RNN_H + sc;

  for (int k0 = 0; k0 < RNN_H; k0 += 32) {
    float xa[16], wa[16];
    #pragma unroll
    for (int j = 0; j < 4; ++j) {
      *(float4*)&xa[j * 4] = *(const float4*)(xp + k0 + j * 4);
      *(float4*)&wa[j * 4] = *(const float4*)(wp + k0 + j * 4);
    }
    __syncthreads();
    bf16x8 h0, l0, h1, l1;
    cvt8_hl(&xa[0], &h0, &l0); cvt8_hl(&xa[8], &h1, &l1);
    *(bf16x8*)&As[0][sr][sc] = h0; *(bf16x8*)&As[1][sr][sc] = l0;
    *(bf16x8*)&As[0][sr][sc + 8] = h1; *(bf16x8*)&As[1][sr][sc + 8] = l1;
    cvt8_hl(&wa[0], &h0, &l0); cvt8_hl(&wa[8], &h1, &l1);
    *(bf16x8*)&Bs[0][sr][sc] = h0; *(bf16x8*)&Bs[1][sr][sc] = l0;
    *(bf16x8*)&Bs[0][sr][sc + 8] = h1; *(bf16x8*)&Bs[1][sr][sc + 8] = l1;
    __syncthreads();
    bf16x8 ah[4], al[4], bh[4], bl[4];
    #pragma unroll
    for (int i = 0; i < 4; ++i) {
      ah[i] = *(const bf16x8*)&As[0][wr * 64 + i * 16 + l15][lq * 8];
      al[i] = *(const bf16x8*)&As[1][wr * 64 + i * 16 + l15][lq * 8];
    }
    #pragma unroll
    for (int j = 0; j < 4; ++j) {
      bh[j] = *(const bf16x8*)&Bs[0][wc * 64 + j * 16 + l15][lq * 8];
      bl[j] = *(const bf16x8*)&Bs[1][wc * 64 + j * 16 + l15][lq * 8];
    }
    #pragma unroll
    for (int i = 0; i < 4; ++i)
      #pragma unroll
      for (int j = 0; j < 4; ++j) {
        acc[i][j] = mfma16b(ah[i], bh[j], acc[i][j]);
        acc[i][j] = mfma16b(al[i], bh[j], acc[i][j]);
        acc[i][j] = mfma16b(ah[i], bl[j], acc[i][j]);
      }
  }

  #pragma unroll
  for (int j = 0; j < 4; ++j) {
    const int col = bn * 128 + wc * 64 + j * 16 + l15;
    const float bias = bih0[col] + bhh0[col];
    #pragma unroll
    for (int i = 0; i < 4; ++i) {
      const int row0 = bm * 128 + wr * 64 + i * 16 + lq * 4;
      #pragma unroll
      for (int r = 0; r < 4; ++r)
        A0[(size_t)(row0 + r) * RNN_H + col] = acc[i][j][r] + bias;
    }
  }
}

// publish progress (R10-proven): drain h stores, block-arrive, store per-block flag
__device__ __forceinline__ void publish(unsigned* slot, unsigned v) {
  asm volatile("s_waitcnt vmcnt(0)" ::: "memory");
  __syncthreads();
  if (threadIdx.x == 0)
    __hip_atomic_store(slot, v, __ATOMIC_RELAXED, __HIP_MEMORY_SCOPE_SYSTEM);
}

// per-wave parallel wait: lanes 0-3 poll this wave's 4 L0-producer flags (>= tProd),
// lanes 4-35 poll all 32 L1 flags (>= tL1, WAR/dependency - monotone so early check ok)
__device__ __forceinline__ void wavewait(const unsigned* fbase, int lane, int w,
                                         int tProd, int tL1) {
  const unsigned* f;
  int tgt;
  if (lane < 4)       { f = fbase + (w * 4 + lane) * FLAG_STRIDE; tgt = tProd; }
  else if (lane < 36) { f = fbase + (12 + lane) * FLAG_STRIDE;    tgt = tL1;  } // 16+(lane-4)
  else                { f = fbase;                                tgt = (int)0x80000000; }
  while (!__all((int)__hip_atomic_load(f, __ATOMIC_RELAXED,
                                       __HIP_MEMORY_SCOPE_SYSTEM) >= tgt))
    __builtin_amdgcn_s_sleep(1);
}

// ---------- Kernel 2: persistent recurrence, batch-split x4 + K-split x4,
// per-wave decoupled flag waits, depth-D ping-pong, publish-early, padded red.
__global__ __launch_bounds__(256) void rnn_rec(
    const float* __restrict__ Whh0,
    const float* __restrict__ Wih1, const float* __restrict__ bih1,
    const float* __restrict__ Whh1, const float* __restrict__ bhh1,
    float* outs,             // d_out: A0 (read), layer-1 outs (write), hT tail
    f16* __restrict__ h0buf, // ws: [D][B][H] fp16 ring
    f16* __restrict__ h1buf, // ws: [D][B][H] fp16 ring
    unsigned* flags, int dmask)
{
  const int bid = blockIdx.x;
  const bool isL0 = bid < L0_NBLK;
  const int tid = threadIdx.x;
  const int w = tid >> 6;         // K-slice 0..3 (256 elems each)
  const int lane = tid & 63;
  const int l15 = lane & 15;
  const int lq = lane >> 4;
  const int swz = l15 & 7;
  const int dlag = dmask;         // D-1 run-ahead slack

  int b0, n0, bs, cs;
  if (isL0) { bs = bid >> 4; cs = bid & 15; b0 = bs * 16; n0 = cs * 64; }
  else { const int b2 = bid - L0_NBLK; bs = b2 >> 5; cs = b2 & 31; b0 = bs * 16; n0 = cs * 32; }

  unsigned* fbase = flags + bs * 48 * FLAG_STRIDE;
  unsigned* myflag = fbase + (isL0 ? cs : 16 + cs) * FLAG_STRIDE;

  const unsigned HBYT = (unsigned)(dmask + 1) * BH * 2u;
  const i32x4 srd_h0 = make_srd(h0buf, HBYT);
  const i32x4 srd_h1 = make_srd(h1buf, HBYT);

  __shared__ __align__(16) f16 Ws[2 * 32 * RNN_H];   // 128 KiB weights (fp16, swizzled)
  __shared__ __align__(16) float red[4][16][68];      // padded: combine reads <=2-way banks

  // ---- stage weights fp32 -> fp16 into LDS, 16B-chunk swizzle: chunk c of row n -> c^(n&7)
  if (isL0) {
    const int n = tid >> 2;             // 0..63
    const int kb = (tid & 3) * 256;
    const float* src = Whh0 + (size_t)(n0 + n) * RNN_H + kb;
    f16* dst = Ws + n * RNN_H;
    #pragma unroll 4
    for (int j = 0; j < 32; ++j) {
      float tmp[8];
      *(float4*)&tmp[0] = *(const float4*)(src + j * 8);
      *(float4*)&tmp[4] = *(const float4*)(src + j * 8 + 4);
      const int c = (kb >> 3) + j;
      *(f16x8*)&dst[((c ^ (n & 7)) << 3)] = cvt8f(tmp);
    }
  } else {
    const int n = tid >> 3;             // 0..31
    const int kb = (tid & 7) * 128;
    #pragma unroll
    for (int m = 0; m < 2; ++m) {
      const float* src = (m ? Whh1 : Wih1) + (size_t)(n0 + n) * RNN_H + kb;
      f16* dst = Ws + m * 32 * RNN_H + n * RNN_H;
      #pragma unroll 4
      for (int j = 0; j < 16; ++j) {
        float tmp[8];
        *(float4*)&tmp[0] = *(const float4*)(src + j * 8);
        *(float4*)&tmp[4] = *(const float4*)(src + j * 8 + 4);
        const int c = (kb >> 3) + j;
        *(f16x8*)&dst[((c ^ (n & 7)) << 3)] = cvt8f(tmp);
      }
    }
  }

  float* hT = outs + OUTS_ELEMS;

  // combine-phase role: one row, a small contiguous col-group per thread
  const int crow = tid & 15;
  const int cg = tid >> 4;            // L0: 4 cols per group; L1: 2 cols per group
  float bias1a = 0.f, bias1b = 0.f;
  if (!isL0) {
    bias1a = bih1[n0 + cg * 2]     + bhh1[n0 + cg * 2];
    bias1b = bih1[n0 + cg * 2 + 1] + bhh1[n0 + cg * 2 + 1];
  }
  __syncthreads();

  if (isL0) {
    f32x4 a0v = *(const f32x4*)&outs[((size_t)(b0 + crow) * RNN_S + 0) * RNN_H + n0 + cg * 4];

    for (int p = 0; p < RNN_S; ++p) {
      // wave needs: its 4 producers done step p-1; WAR: all L1 done step p-D
      wavewait(fbase, lane, w, p, p - dlag);
      if (p > 0) {
        const int hb = (((p - 1) & dmask) * BH + (b0 + l15) * RNN_H + w * 256 + lq * 8) * 2;
        f32x4 acc[4] = {};
        #pragma unroll
        for (int ks = 0; ks < 8; ++ks) {
          f16x8 hx = ld_h(srd_h0, hb + ks * 64);
          const int c = ((w * 32 + ks * 4 + lq) ^ swz) << 3;
          #pragma unroll
          for (int ct = 0; ct < 4; ++ct)
            acc[ct] = mfma16f(hx, *(const f16x8*)&Ws[(ct * 16 + l15) * RNN_H + c], acc[ct]);
        }
        #pragma unroll
        for (int ct = 0; ct < 4; ++ct)
          #pragma unroll
          for (int r = 0; r < 4; ++r)
            red[w][lq * 4 + r][ct * 16 + l15] = acc[ct][r];
      }
      __syncthreads();
      f32x4 s4 = a0v;
      if (p > 0) {
        #pragma unroll
        for (int ww = 0; ww < 4; ++ww)
          s4 += *(const f32x4*)&red[ww][crow][cg * 4];
      }
      float vals[4];
      #pragma unroll
      for (int j = 0; j < 4; ++j) vals[j] = tanhf(s4[j]);
      st_sys_u64(&h0buf[(size_t)(p & dmask) * BH + (size_t)(b0 + crow) * RNN_H + n0 + cg * 4],
                 pack4f16(vals));
      publish(myflag, (unsigned)(p + 1));    // release h0(p) ASAP
      if (p == RNN_S - 1) {                  // off critical path
        f32x4 hv = { vals[0], vals[1], vals[2], vals[3] };
        *(f32x4*)&hT[(size_t)(b0 + crow) * RNN_H + n0 + cg * 4] = hv;
      }
      if (p + 1 < RNN_S)                     // A0 prefetch overlaps next wait
        a0v = *(const f32x4*)&outs[((size_t)(b0 + crow) * RNN_S + (p + 1)) * RNN_H + n0 + cg * 4];
    }
  } else {
    for (int t = 0; t < RNN_S; ++t) {
      // wave needs: its 4 L0 producers done step t (flags >= t+1); all L1 done t-1 (>= t)
      wavewait(fbase, lane, w, t + 1, t);
      const int hb0 = ((t & dmask) * BH + (b0 + l15) * RNN_H + w * 256 + lq * 8) * 2;
      f32x4 acc[2] = {};
      if (t > 0) {
        const int hb1 = (((t - 1) & dmask) * BH + (b0 + l15) * RNN_H + w * 256 + lq * 8) * 2;
        #pragma unroll
        for (int ks = 0; ks < 8; ++ks) {
          f16x8 hx = ld_h(srd_h0, hb0 + ks * 64);
          f16x8 gx = ld_h(srd_h1, hb1 + ks * 64);
          const int c = ((w * 32 + ks * 4 + lq) ^ swz) << 3;
          #pragma unroll
          for (int ct = 0; ct < 2; ++ct) {
            acc[ct] = mfma16f(hx, *(const f16x8*)&Ws[(ct * 16 + l15) * RNN_H + c], acc[ct]);
            acc[ct] = mfma16f(gx, *(const f16x8*)&Ws[32 * RNN_H + (ct * 16 + l15) * RNN_H + c], acc[ct]);
          }
        }
      } else {
        #pragma unroll
        for (int ks = 0; ks < 8; ++ks) {
          f16x8 hx = ld_h(srd_h0, hb0 + ks * 64);
          const int c = ((w * 32 + ks * 4 + lq) ^ swz) << 3;
          #pragma unroll
          for (int ct = 0; ct < 2; ++ct)
            acc[ct] = mfma16f(hx, *(const f16x8*)&Ws[(ct * 16 + l15) * RNN_H + c], acc[ct]);
        }
      }
      #pragma unroll
      for (int ct = 0; ct < 2; ++ct)
        #pragma unroll
        for (int r = 0; r < 4; ++r)
          red[w][lq * 4 + r][ct * 16 + l15] = acc[ct][r];
      __syncthreads();
      f32x2 s2 = { bias1a, bias1b };
      #pragma unroll
      for (int ww = 0; ww < 4; ++ww)
        s2 += *(const f32x2*)&red[ww][crow][cg * 2];
      const float v0 = tanhf(s2[0]), v1 = tanhf(s2[1]);
      st_sys_u32(&h1buf[(size_t)(t & dmask) * BH + (size_t)(b0 + crow) * RNN_H + n0 + cg * 2],
                 pack2f16(v0, v1));
      publish(myflag, (unsigned)(t + 1));    // release h1(t) ASAP
      {                                      // outs/hT off critical path
        f32x2 ov = { v0, v1 };
        *(f32x2*)&outs[((size_t)(b0 + crow) * RNN_S + t) * RNN_H + n0 + cg * 2] = ov;
        if (t == RNN_S - 1)
          *(f32x2*)&hT[(size_t)BH + (size_t)(b0 + crow) * RNN_H + n0 + cg * 2] = ov;
      }
    }
  }
}

extern "C" void kernel_launch(void* const* d_in, const int* in_sizes, int n_in,
                              void* d_out, int out_size, void* d_ws, size_t ws_size,
                              hipStream_t stream) {
  const float* x    = (const float*)d_in[0];
  const float* Wih0 = (const float*)d_in[1];
  const float* bih0 = (const float*)d_in[2];
  const float* Whh0 = (const float*)d_in[3];
  const float* bhh0 = (const float*)d_in[4];
  const float* Wih1 = (const float*)d_in[5];
  const float* bih1 = (const float*)d_in[6];
  const float* Whh1 = (const float*)d_in[7];
  const float* bhh1 = (const float*)d_in[8];
  float* outs = (float*)d_out;

  // ws layout: [flags 32KiB][h0buf D*128KiB][h1buf D*128KiB]
  const size_t flagBytes = 32768;
  const size_t need4 = flagBytes + 2 * (size_t)4 * BH * sizeof(f16);   // ~1.03 MiB
  const int D = (ws_size >= need4) ? 4 : 2;
  unsigned* flags = (unsigned*)d_ws;
  f16* h0buf = (f16*)((char*)d_ws + flagBytes);
  f16* h1buf = h0buf + (size_t)D * BH;

  a0_gemm<<<2048, 256, 0, stream>>>(x, Wih0, bih0, bhh0, outs, flags);
  rnn_rec<<<NBLK, 256, 0, stream>>>(Whh0, Wih1, bih1, Whh1, bhh1, outs,
                                    h0buf, h1buf, flags, D - 1);
}

// Round 14
// 2161.273 us; speedup vs baseline: 1.3603x; 1.0186x over previous
//
#include <hip/hip_runtime.h>
#include <hip/hip_bf16.h>

#define RNN_B 64
#define RNN_S 512
#define RNN_H 1024
#define BH (RNN_B * RNN_H)
#define L0_NBLK 64            // 16 col-slices x 4 batch-slices (64 cols x 16 rows each)
#define L1_NBLK 128           // 32 col-slices x 4 batch-slices (32 cols x 16 rows each)
#define NBLK (L0_NBLK + L1_NBLK)
#define NFLAGS 192            // 4 domains x 48 flags
#define FLAG_STRIDE 32
#define OUTS_ELEMS ((size_t)RNN_B * RNN_S * RNN_H)

typedef _Float16 f16;
typedef __attribute__((ext_vector_type(8))) _Float16 f16x8;
typedef __attribute__((ext_vector_type(8))) short bf16x8;
typedef __attribute__((ext_vector_type(4))) float f32x4;
typedef __attribute__((ext_vector_type(2))) float f32x2;
typedef __attribute__((ext_vector_type(4))) int i32x4;

// raw buffer load, cachepolicy 17 = sc0|sc1: bypass L1/L2, read coherence point.
__device__ f32x4 __rnn_rawbufload_x4(i32x4 srsrc, int voffset, int soffset,
                                     int cachepolicy) __asm("llvm.amdgcn.raw.buffer.load.v4f32");

__device__ __forceinline__ i32x4 make_srd(const void* p, unsigned bytes) {
  i32x4 r;
  r[0] = (int)(unsigned)(unsigned long long)p;
  r[1] = (int)((unsigned long long)p >> 32);
  r[2] = (int)bytes;
  r[3] = 0x00020000;
  return r;
}

__device__ __forceinline__ f16x8 ld_h(i32x4 srd, int byteoff) {
  union { f32x4 f; f16x8 h; } u;
  u.f = __rnn_rawbufload_x4(srd, byteoff, 0, 17);
  return u.h;
}

// write-through stores to the coherence point (proven R5-R13)
__device__ __forceinline__ void st_sys_u32(void* p, unsigned v) {
  asm volatile("global_store_dword %0, %1, off sc0 sc1" :: "v"(p), "v"(v) : "memory");
}
__device__ __forceinline__ void st_sys_u64(void* p, unsigned long long v) {
  asm volatile("global_store_dwordx2 %0, %1, off sc0 sc1" :: "v"(p), "v"(v) : "memory");
}

__device__ __forceinline__ unsigned pack2f16(float a, float b) {
  union { f16 h[2]; unsigned u; } v;
  v.h[0] = (f16)a; v.h[1] = (f16)b;
  return v.u;
}
__device__ __forceinline__ unsigned long long pack4f16(const float* f) {
  union { f16 h[4]; unsigned long long u; } v;
  #pragma unroll
  for (int i = 0; i < 4; ++i) v.h[i] = (f16)f[i];
  return v.u;
}

__device__ __forceinline__ short f2bf(float f) {
  union { float f; unsigned u; } v; v.f = f;
  return (short)((v.u + 0x7FFFu + ((v.u >> 16) & 1u)) >> 16);
}
__device__ __forceinline__ float bf2f(short h) {
  union { unsigned u; float f; } v; v.u = ((unsigned)(unsigned short)h) << 16;
  return v.f;
}
__device__ __forceinline__ f32x4 mfma16b(bf16x8 a, bf16x8 b, f32x4 c) {
  return __builtin_amdgcn_mfma_f32_16x16x32_bf16(a, b, c, 0, 0, 0);
}
__device__ __forceinline__ f32x4 mfma16f(f16x8 a, f16x8 b, f32x4 c) {
  return __builtin_amdgcn_mfma_f32_16x16x32_f16(a, b, c, 0, 0, 0);
}
__device__ __forceinline__ void cvt8_hl(const float* f, bf16x8* hi, bf16x8* lo) {
  #pragma unroll
  for (int i = 0; i < 8; ++i) {
    short h = f2bf(f[i]);
    (*hi)[i] = h;
    (*lo)[i] = f2bf(f[i] - bf2f(h));
  }
}
__device__ __forceinline__ f16x8 cvt8f(const float* f) {
  f16x8 r;
  #pragma unroll
  for (int i = 0; i < 8; ++i) r[i] = (f16)f[i];
  return r;
}

// ---------- Kernel 1: A0 = x @ W_ih0^T + b_ih0 + b_hh0 (split-bf16 3-pass, ~fp32 accurate)
__global__ __launch_bounds__(256) void a0_gemm(
    const float* __restrict__ x, const float* __restrict__ Wih0,
    const float* __restrict__ bih0, const float* __restrict__ bhh0,
    float* __restrict__ A0, unsigned* __restrict__ flags)
{
  if (blockIdx.x == 0) {
    for (int i = threadIdx.x; i < NFLAGS * FLAG_STRIDE; i += 256)
      __hip_atomic_store(&flags[i], 0u, __ATOMIC_RELAXED, __HIP_MEMORY_SCOPE_SYSTEM);
  }
  const int bn = blockIdx.x & 7;
  const int bm = blockIdx.x >> 3;
  const int tid = threadIdx.x;
  const int lane = tid & 63;
  const int w = tid >> 6;
  const int wr = w >> 1, wc = w & 1;
  const int l15 = lane & 15, lq = lane >> 4;

  __shared__ short As[2][128][40];
  __shared__ short Bs[2][128][40];

  f32x4 acc[4][4] = {};

  const int sr = tid >> 1;
  const int sc = (tid & 1) << 4;
  const float* xp = x + (size_t)(bm * 128 + sr) * RNN_H + sc;
  const float* wp = Wih0 + (size_t)(bn * 128 + sr) * RNN_H + sc;

  for (int k0 = 0; k0 < RNN_H; k0 += 32) {
    float xa[16], wa[16];
    #pragma unroll
    for (int j = 0; j < 4; ++j) {
      *(float4*)&xa[j * 4] = *(const float4*)(xp + k0 + j * 4);
      *(float4*)&wa[j * 4] = *(const float4*)(wp + k0 + j * 4);
    }
    __syncthreads();
    bf16x8 h0, l0, h1, l1;
    cvt8_hl(&xa[0], &h0, &l0); cvt8_hl(&xa[8], &h1, &l1);
    *(bf16x8*)&As[0][sr][sc] = h0; *(bf16x8*)&As[1][sr][sc] = l0;
    *(bf16x8*)&As[0][sr][sc + 8] = h1; *(bf16x8*)&As[1][sr][sc + 8] = l1;
    cvt8_hl(&wa[0], &h0, &l0); cvt8_hl(&wa[8], &h1, &l1);
    *(bf16x8*)&Bs[0][sr][sc] = h0; *(bf16x8*)&Bs[1][sr][sc] = l0;
    *(bf16x8*)&Bs[0][sr][sc + 8] = h1; *(bf16x8*)&Bs[1][sr][sc + 8] = l1;
    __syncthreads();
    bf16x8 ah[4], al[4], bh[4], bl[4];
    #pragma unroll
    for (int i = 0; i < 4; ++i) {
      ah[i] = *(const bf16x8*)&As[0][wr * 64 + i * 16 + l15][lq * 8];
      al[i] = *(const bf16x8*)&As[1][wr * 64 + i * 16 + l15][lq * 8];
    }
    #pragma unroll
    for (int j = 0; j < 4; ++j) {
      bh[j] = *(const bf16x8*)&Bs[0][wc * 64 + j * 16 + l15][lq * 8];
      bl[j] = *(const bf16x8*)&Bs[1][wc * 64 + j * 16 + l15][lq * 8];
    }
    #pragma unroll
    for (int i = 0; i < 4; ++i)
      #pragma unroll
      for (int j = 0; j < 4; ++j) {
        acc[i][j] = mfma16b(ah[i], bh[j], acc[i][j]);
        acc[i][j] = mfma16b(al[i], bh[j], acc[i][j]);
        acc[i][j] = mfma16b(ah[i], bl[j], acc[i][j]);
      }
  }

  #pragma unroll
  for (int j = 0; j < 4; ++j) {
    const int col = bn * 128 + wc * 64 + j * 16 + l15;
    const float bias = bih0[col] + bhh0[col];
    #pragma unroll
    for (int i = 0; i < 4; ++i) {
      const int row0 = bm * 128 + wr * 64 + i * 16 + lq * 4;
      #pragma unroll
      for (int r = 0; r < 4; ++r)
        A0[(size_t)(row0 + r) * RNN_H + col] = acc[i][j][r] + bias;
    }
  }
}

// publish progress (R10-proven): drain h stores, block-arrive, store per-block flag
__device__ __forceinline__ void publish(unsigned* slot, unsigned v) {
  asm volatile("s_waitcnt vmcnt(0)" ::: "memory");
  __syncthreads();
  if (threadIdx.x == 0)
    __hip_atomic_store(slot, v, __ATOMIC_RELAXED, __HIP_MEMORY_SCOPE_SYSTEM);
}

// L0 wave wait: lanes 0-3 poll this wave's 4 L0-producer flags (>= tProd),
// lanes 4-35 poll all 32 L1 flags (>= tL1, WAR slack - off critical path)
__device__ __forceinline__ void wavewait0(const unsigned* fbase, int lane, int w,
                                          int tProd, int tL1) {
  const unsigned* f;
  int tgt;
  if (lane < 4)       { f = fbase + (w * 4 + lane) * FLAG_STRIDE; tgt = tProd; }
  else if (lane < 36) { f = fbase + (12 + lane) * FLAG_STRIDE;    tgt = tL1;  } // 16+(lane-4)
  else                { f = fbase;                                tgt = (int)0x80000000; }
  while (!__all((int)__hip_atomic_load(f, __ATOMIC_RELAXED,
                                       __HIP_MEMORY_SCOPE_SYSTEM) >= tgt))
    __builtin_amdgcn_s_sleep(1);
}

// L1 wave wait (R14): lanes 0-3 poll its 4 L0 h0-producers (>= tL0);
// lanes 8-15 poll its 8 L1 h1-co-slice producers (>= tSelf). Block-level WAR
// (all-32 >= t at h1-write time) is implied by the union of the 4 waves' waits
// + the pre-combine barrier, so no explicit all-32 poll is needed.
__device__ __forceinline__ void wavewait1(const unsigned* fbase, int lane, int w,
                                          int tL0, int tSelf) {
  const unsigned* f;
  int tgt;
  if (lane < 4)                    { f = fbase + (w * 4 + lane) * FLAG_STRIDE;          tgt = tL0;   }
  else if (lane >= 8 && lane < 16) { f = fbase + (16 + w * 8 + (lane - 8)) * FLAG_STRIDE; tgt = tSelf; }
  else                             { f = fbase;                                          tgt = (int)0x80000000; }
  while (!__all((int)__hip_atomic_load(f, __ATOMIC_RELAXED,
                                       __HIP_MEMORY_SCOPE_SYSTEM) >= tgt))
    __builtin_amdgcn_s_sleep(1);
}

// ---------- Kernel 2: persistent recurrence, batch-split x4 + K-split x4,
// per-wave decoupled flag waits (min fan-in), depth-D ping-pong, publish-early.
__global__ __launch_bounds__(256) void rnn_rec(
    const float* __restrict__ Whh0,
    const float* __restrict__ Wih1, const float* __restrict__ bih1,
    const float* __restrict__ Whh1, const float* __restrict__ bhh1,
    float* outs,             // d_out: A0 (read), layer-1 outs (write), hT tail
    f16* __restrict__ h0buf, // ws: [D][B][H] fp16 ring
    f16* __restrict__ h1buf, // ws: [D][B][H] fp16 ring
    unsigned* flags, int dmask)
{
  const int bid = blockIdx.x;
  const bool isL0 = bid < L0_NBLK;
  const int tid = threadIdx.x;
  const int w = tid >> 6;         // K-slice 0..3 (256 elems each)
  const int lane = tid & 63;
  const int l15 = lane & 15;
  const int lq = lane >> 4;
  const int swz = l15 & 7;
  const int dlag = dmask;         // D-1 run-ahead slack

  int b0, n0, bs, cs;
  if (isL0) { bs = bid >> 4; cs = bid & 15; b0 = bs * 16; n0 = cs * 64; }
  else { const int b2 = bid - L0_NBLK; bs = b2 >> 5; cs = b2 & 31; b0 = bs * 16; n0 = cs * 32; }

  unsigned* fbase = flags + bs * 48 * FLAG_STRIDE;
  unsigned* myflag = fbase + (isL0 ? cs : 16 + cs) * FLAG_STRIDE;

  const unsigned HBYT = (unsigned)(dmask + 1) * BH * 2u;
  const i32x4 srd_h0 = make_srd(h0buf, HBYT);
  const i32x4 srd_h1 = make_srd(h1buf, HBYT);

  __shared__ __align__(16) f16 Ws[2 * 32 * RNN_H];   // 128 KiB weights (fp16, swizzled)
  __shared__ __align__(16) float red[4][16][68];      // padded: combine reads <=2-way banks

  // ---- stage weights fp32 -> fp16 into LDS, 16B-chunk swizzle: chunk c of row n -> c^(n&7)
  if (isL0) {
    const int n = tid >> 2;             // 0..63
    const int kb = (tid & 3) * 256;
    const float* src = Whh0 + (size_t)(n0 + n) * RNN_H + kb;
    f16* dst = Ws + n * RNN_H;
    #pragma unroll 4
    for (int j = 0; j < 32; ++j) {
      float tmp[8];
      *(float4*)&tmp[0] = *(const float4*)(src + j * 8);
      *(float4*)&tmp[4] = *(const float4*)(src + j * 8 + 4);
      const int c = (kb >> 3) + j;
      *(f16x8*)&dst[((c ^ (n & 7)) << 3)] = cvt8f(tmp);
    }
  } else {
    const int n = tid >> 3;             // 0..31
    const int kb = (tid & 7) * 128;
    #pragma unroll
    for (int m = 0; m < 2; ++m) {
      const float* src = (m ? Whh1 : Wih1) + (size_t)(n0 + n) * RNN_H + kb;
      f16* dst = Ws + m * 32 * RNN_H + n * RNN_H;
      #pragma unroll 4
      for (int j = 0; j < 16; ++j) {
        float tmp[8];
        *(float4*)&tmp[0] = *(const float4*)(src + j * 8);
        *(float4*)&tmp[4] = *(const float4*)(src + j * 8 + 4);
        const int c = (kb >> 3) + j;
        *(f16x8*)&dst[((c ^ (n & 7)) << 3)] = cvt8f(tmp);
      }
    }
  }

  float* hT = outs + OUTS_ELEMS;

  // combine-phase role: one row, a small contiguous col-group per thread
  const int crow = tid & 15;
  const int cg = tid >> 4;            // L0: 4 cols per group; L1: 2 cols per group
  float bias1a = 0.f, bias1b = 0.f;
  if (!isL0) {
    bias1a = bih1[n0 + cg * 2]     + bhh1[n0 + cg * 2];
    bias1b = bih1[n0 + cg * 2 + 1] + bhh1[n0 + cg * 2 + 1];
  }
  __syncthreads();

  if (isL0) {
    f32x4 a0v = *(const f32x4*)&outs[((size_t)(b0 + crow) * RNN_S + 0) * RNN_H + n0 + cg * 4];

    for (int p = 0; p < RNN_S; ++p) {
      // wave needs: its 4 producers done step p-1; WAR: all L1 done step p-D
      wavewait0(fbase, lane, w, p, p - dlag);
      if (p > 0) {
        const int hb = (((p - 1) & dmask) * BH + (b0 + l15) * RNN_H + w * 256 + lq * 8) * 2;
        f32x4 acc[4] = {};
        #pragma unroll
        for (int ks = 0; ks < 8; ++ks) {
          f16x8 hx = ld_h(srd_h0, hb + ks * 64);
          const int c = ((w * 32 + ks * 4 + lq) ^ swz) << 3;
          #pragma unroll
          for (int ct = 0; ct < 4; ++ct)
            acc[ct] = mfma16f(hx, *(const f16x8*)&Ws[(ct * 16 + l15) * RNN_H + c], acc[ct]);
        }
        #pragma unroll
        for (int ct = 0; ct < 4; ++ct)
          #pragma unroll
          for (int r = 0; r < 4; ++r)
            red[w][lq * 4 + r][ct * 16 + l15] = acc[ct][r];
      }
      __syncthreads();
      f32x4 s4 = a0v;
      if (p > 0) {
        #pragma unroll
        for (int ww = 0; ww < 4; ++ww)
          s4 += *(const f32x4*)&red[ww][crow][cg * 4];
      }
      float vals[4];
      #pragma unroll
      for (int j = 0; j < 4; ++j) vals[j] = tanhf(s4[j]);
      st_sys_u64(&h0buf[(size_t)(p & dmask) * BH + (size_t)(b0 + crow) * RNN_H + n0 + cg * 4],
                 pack4f16(vals));
      publish(myflag, (unsigned)(p + 1));    // release h0(p) ASAP
      if (p == RNN_S - 1) {                  // off critical path
        f32x4 hv = { vals[0], vals[1], vals[2], vals[3] };
        *(f32x4*)&hT[(size_t)(b0 + crow) * RNN_H + n0 + cg * 4] = hv;
      }
      if (p + 1 < RNN_S)                     // A0 prefetch overlaps next wait
        a0v = *(const f32x4*)&outs[((size_t)(b0 + crow) * RNN_S + (p + 1)) * RNN_H + n0 + cg * 4];
    }
  } else {
    for (int t = 0; t < RNN_S; ++t) {
      // wave needs: its 4 L0 producers done step t (>= t+1); its 8 h1 producers done t-1 (>= t)
      wavewait1(fbase, lane, w, t + 1, t);
      const int hb0 = ((t & dmask) * BH + (b0 + l15) * RNN_H + w * 256 + lq * 8) * 2;
      f32x4 acc[2] = {};
      if (t > 0) {
        const int hb1 = (((t - 1) & dmask) * BH + (b0 + l15) * RNN_H + w * 256 + lq * 8) * 2;
        #pragma unroll
        for (int ks = 0; ks < 8; ++ks) {
          f16x8 hx = ld_h(srd_h0, hb0 + ks * 64);
          f16x8 gx = ld_h(srd_h1, hb1 + ks * 64);
          const int c = ((w * 32 + ks * 4 + lq) ^ swz) << 3;
          #pragma unroll
          for (int ct = 0; ct < 2; ++ct) {
            acc[ct] = mfma16f(hx, *(const f16x8*)&Ws[(ct * 16 + l15) * RNN_H + c], acc[ct]);
            acc[ct] = mfma16f(gx, *(const f16x8*)&Ws[32 * RNN_H + (ct * 16 + l15) * RNN_H + c], acc[ct]);
          }
        }
      } else {
        #pragma unroll
        for (int ks = 0; ks < 8; ++ks) {
          f16x8 hx = ld_h(srd_h0, hb0 + ks * 64);
          const int c = ((w * 32 + ks * 4 + lq) ^ swz) << 3;
          #pragma unroll
          for (int ct = 0; ct < 2; ++ct)
            acc[ct] = mfma16f(hx, *(const f16x8*)&Ws[(ct * 16 + l15) * RNN_H + c], acc[ct]);
        }
      }
      #pragma unroll
      for (int ct = 0; ct < 2; ++ct)
        #pragma unroll
        for (int r = 0; r < 4; ++r)
          red[w][lq * 4 + r][ct * 16 + l15] = acc[ct][r];
      __syncthreads();
      f32x2 s2 = { bias1a, bias1b };
      #pragma unroll
      for (int ww = 0; ww < 4; ++ww)
        s2 += *(const f32x2*)&red[ww][crow][cg * 2];
      const float v0 = tanhf(s2[0]), v1 = tanhf(s2[1]);
      st_sys_u32(&h1buf[(size_t)(t & dmask) * BH + (size_t)(b0 + crow) * RNN_H + n0 + cg * 2],
                 pack2f16(v0, v1));
      publish(myflag, (unsigned)(t + 1));    // release h1(t) ASAP
      {                                      // outs/hT off critical path
        f32x2 ov = { v0, v1 };
        *(f32x2*)&outs[((size_t)(b0 + crow) * RNN_S + t) * RNN_H + n0 + cg * 2] = ov;
        if (t == RNN_S - 1)
          *(f32x2*)&hT[(size_t)BH + (size_t)(b0 + crow) * RNN_H + n0 + cg * 2] = ov;
      }
    }
  }
}

extern "C" void kernel_launch(void* const* d_in, const int* in_sizes, int n_in,
                              void* d_out, int out_size, void* d_ws, size_t ws_size,
                              hipStream_t stream) {
  const float* x    = (const float*)d_in[0];
  const float* Wih0 = (const float*)d_in[1];
  const float* bih0 = (const float*)d_in[2];
  const float* Whh0 = (const float*)d_in[3];
  const float* bhh0 = (const float*)d_in[4];
  const float* Wih1 = (const float*)d_in[5];
  const float* bih1 = (const float*)d_in[6];
  const float* Whh1 = (const float*)d_in[7];
  const float* bhh1 = (const float*)d_in[8];
  float* outs = (float*)d_out;

  // ws layout: [flags 32KiB][h0buf D*128KiB][h1buf D*128KiB]
  const size_t flagBytes = 32768;
  const size_t need4 = flagBytes + 2 * (size_t)4 * BH * sizeof(f16);   // ~1.03 MiB
  const int D = (ws_size >= need4) ? 4 : 2;
  unsigned* flags = (unsigned*)d_ws;
  f16* h0buf = (f16*)((char*)d_ws + flagBytes);
  f16* h1buf = h0buf + (size_t)D * BH;

  a0_gemm<<<2048, 256, 0, stream>>>(x, Wih0, bih0, bhh0, outs, flags);
  rnn_rec<<<NBLK, 256, 0, stream>>>(Whh0, Wih1, bih1, Whh1, bhh1, outs,
                                    h0buf, h1buf, flags, D - 1);
}